// Round 19
// baseline (175.684 us; speedup 1.0000x reference)
//
#include <hip/hip_runtime.h>

#define DFEAT 4096
#define NTH 256

typedef float2 cpx;

__device__ __forceinline__ cpx cmulf(cpx a, cpx b) {
  return make_float2(a.x * b.x - a.y * b.y, a.x * b.y + a.y * b.x);
}

// pad 1 cpx every 16: uniform bank spread for stride-256 reads and stride-16 writes
#define IDX(i) ((i) + ((i) >> 4))
#define NPAD (DFEAT + DFEAT / 16)   // 4352 cpx = 34816 B

// sin/cos in REVOLUTIONS (hardware v_sin_f32 semantics); args here in [0, ~0.0625]
__device__ __forceinline__ float sin_rev(float rev) {
#if __has_builtin(__builtin_amdgcn_sinf)
  return __builtin_amdgcn_sinf(rev);
#else
  return __sinf(rev * 6.28318530717958647692f);
#endif
}
__device__ __forceinline__ float cos_rev(float rev) {
#if __has_builtin(__builtin_amdgcn_cosf)
  return __builtin_amdgcn_cosf(rev);
#else
  return __cosf(rev * 6.28318530717958647692f);
#endif
}

// DFT4 with sign SGN (-1 fwd, +1 inv), in-place on 4 cpx: out[s] in slot s
template <int SGN>
__device__ __forceinline__ void dft4(cpx& p0, cpx& p1, cpx& p2, cpx& p3) {
  cpx t0 = make_float2(p0.x + p2.x, p0.y + p2.y);
  cpx t1 = make_float2(p0.x - p2.x, p0.y - p2.y);
  cpx t2 = make_float2(p1.x + p3.x, p1.y + p3.y);
  cpx t3 = make_float2(p1.x - p3.x, p1.y - p3.y);
  cpx it3 = (SGN > 0) ? make_float2(-t3.y, t3.x) : make_float2(t3.y, -t3.x);
  p0 = make_float2(t0.x + t2.x, t0.y + t2.y);
  p2 = make_float2(t0.x - t2.x, t0.y - t2.y);
  p1 = make_float2(t1.x + it3.x, t1.y + it3.y);
  p3 = make_float2(t1.x - it3.x, t1.y - it3.y);
}

// W16^t = exp(SGN*2πi*t/16), compile-time t ∈ {1,2,3,4,6,9}
template <int SGN>
__device__ __forceinline__ cpx w16c(int t) {
  constexpr float C[10] = {1.f, 0.92387953251f, 0.70710678119f, 0.38268343236f, 0.f,
                           0.f, -0.70710678119f, 0.f, 0.f, -0.92387953251f};
  constexpr float S[10] = {0.f, 0.38268343236f, 0.70710678119f, 0.92387953251f, 1.f,
                           0.f, 0.70710678119f, 0.f, 0.f, -0.38268343236f};
  return make_float2(C[t], (SGN > 0) ? S[t] : -S[t]);
}

// 16-pt DFT, in-place: X[s] = sum_r v[r] exp(SGN 2πi rs/16), X[s] left in v[s].
template <int SGN>
__device__ __forceinline__ void dft16(cpx v[16]) {
#pragma unroll
  for (int r1 = 0; r1 < 4; ++r1) dft4<SGN>(v[r1], v[r1 + 4], v[r1 + 8], v[r1 + 12]);
  // v[r1 + 4*s1] = A[r1][s1]; apply W16^(r1*s1)
  v[5]  = cmulf(v[5],  w16c<SGN>(1));
  v[9]  = cmulf(v[9],  w16c<SGN>(2));
  v[13] = cmulf(v[13], w16c<SGN>(3));
  v[6]  = cmulf(v[6],  w16c<SGN>(2));
  v[10] = cmulf(v[10], w16c<SGN>(4));
  v[14] = cmulf(v[14], w16c<SGN>(6));
  v[7]  = cmulf(v[7],  w16c<SGN>(3));
  v[11] = cmulf(v[11], w16c<SGN>(6));
  v[15] = cmulf(v[15], w16c<SGN>(9));
  cpx t[16];
#pragma unroll
  for (int s1 = 0; s1 < 4; ++s1) {
    cpx p0 = v[4 * s1 + 0], p1 = v[4 * s1 + 1], p2 = v[4 * s1 + 2], p3 = v[4 * s1 + 3];
    dft4<SGN>(p0, p1, p2, p3);   // sum over r1; output slot q = s2
    t[s1] = p0; t[s1 + 4] = p1; t[s1 + 8] = p2; t[s1 + 12] = p3;
  }
#pragma unroll
  for (int s = 0; s < 16; ++s) v[s] = t[s];
}

// v[r] *= w^r where w = exp(SGN*2πi*rev) and base = exp(-2πi*rev) (FORWARD sign).
// SGN<0 uses base as-is; SGN>0 uses conj(base). [R18 bug: ternary was inverted.]
// Binary powering: dependency depth 4 (vs 14-deep serial chain).
template <int SGN>
__device__ __forceinline__ void twiddle16(cpx v[16], cpx base) {
  cpx w1 = (SGN > 0) ? make_float2(base.x, -base.y) : base;
  cpx w2 = cmulf(w1, w1);
  cpx w4 = cmulf(w2, w2);
  cpx w8 = cmulf(w4, w4);
  cpx w3 = cmulf(w2, w1);
  cpx w5 = cmulf(w4, w1);
  cpx w6 = cmulf(w4, w2);
  cpx w7 = cmulf(w4, w3);
  cpx w9 = cmulf(w8, w1);
  cpx w10 = cmulf(w8, w2);
  cpx w11 = cmulf(w8, w3);
  cpx w12 = cmulf(w8, w4);
  cpx w13 = cmulf(w8, w5);
  cpx w14 = cmulf(w8, w6);
  cpx w15 = cmulf(w8, w7);
  v[1] = cmulf(v[1], w1);   v[2] = cmulf(v[2], w2);   v[3] = cmulf(v[3], w3);
  v[4] = cmulf(v[4], w4);   v[5] = cmulf(v[5], w5);   v[6] = cmulf(v[6], w6);
  v[7] = cmulf(v[7], w7);   v[8] = cmulf(v[8], w8);   v[9] = cmulf(v[9], w9);
  v[10] = cmulf(v[10], w10); v[11] = cmulf(v[11], w11); v[12] = cmulf(v[12], w12);
  v[13] = cmulf(v[13], w13); v[14] = cmulf(v[14], w14); v[15] = cmulf(v[15], w15);
}

// 4096-pt FFT, radix-16 Stockham, 3 stages, 256 threads, 16 cpx/thread.
// tw1 = exp(-2πi (j&15)/256), tw2 = exp(-2πi j/4096): forward-sign bases,
// computed ONCE per thread and shared by all 4 FFT calls (conjugated for INV).
template <int SGN>
__device__ __forceinline__ void fft_exchange(cpx v[16], cpx* B, int j,
                                             cpx tw1, cpx tw2) {
  dft16<SGN>(v);                                  // st0 (Ns=1, no twiddle)
  __syncthreads();                                // prior consumers of B done
#pragma unroll
  for (int s = 0; s < 16; ++s) B[IDX(16 * j + s)] = v[s];
  __syncthreads();
#pragma unroll
  for (int r = 0; r < 16; ++r) v[r] = B[IDX(j + 256 * r)];
  __syncthreads();                                // all reads before in-place writes
  twiddle16<SGN>(v, tw1);
  dft16<SGN>(v);                                  // st1 (Ns=16)
#pragma unroll
  for (int s = 0; s < 16; ++s) B[IDX(256 * (j >> 4) + (j & 15) + 16 * s)] = v[s];
  __syncthreads();
#pragma unroll
  for (int r = 0; r < 16; ++r) v[r] = B[IDX(j + 256 * r)];
  twiddle16<SGN>(v, tw2);
  dft16<SGN>(v);                                  // st2 (Ns=256) -> natural order
}

// Ghat[r] = FFT(g[r]) / 4096
__global__ __launch_bounds__(NTH, 1) void ghat_kernel(const float* __restrict__ g,
                                                      cpx* __restrict__ Ghat) {
  __shared__ cpx B[NPAD];
  const int rr = blockIdx.x;
  const int j = threadIdx.x;
  // forward-sign twiddle bases (negated sin: exp(-2πi rev))
  cpx tw1 = make_float2(cos_rev((float)(j & 15) * (1.0f / 256.0f)),
                        -sin_rev((float)(j & 15) * (1.0f / 256.0f)));
  cpx tw2 = make_float2(cos_rev((float)j * (1.0f / 4096.0f)),
                        -sin_rev((float)j * (1.0f / 4096.0f)));
  cpx v[16];
#pragma unroll
  for (int r = 0; r < 16; ++r) {
    int pos = j + 256 * r;
    v[r] = make_float2(g[rr * DFEAT + pos], 0.0f);
  }
  fft_exchange<-1>(v, B, j, tw1, tw2);
  const float inv = 1.0f / 4096.0f;
#pragma unroll
  for (int s = 0; s < 16; ++s) {
    int pos = j + 256 * s;
    Ghat[rr * DFEAT + pos] = make_float2(v[s].x * inv, v[s].y * inv);
  }
}

// One block = one row PAIR (two-for-one):
//   w = x1*psi + i*x2*psi ; W = FFT(w), parked in THREAD-PRIVATE LDS slots
//   for r: z = IFFT(W*Ghat_r); a1 += Re(z)*omega_r; a2 += Im(z)*omega_r
__global__ __launch_bounds__(NTH, 2) void fftconv_kernel(
    const float* __restrict__ x, const float* __restrict__ psi,
    const float* __restrict__ omega, const float* __restrict__ bias,
    const cpx* __restrict__ Ghat, float* __restrict__ out) {
  __shared__ cpx B[NPAD];
  __shared__ cpx Wl[NPAD];
  const int p = blockIdx.x;
  const int j = threadIdx.x;
  const float* x1 = x + ((size_t)(2 * p)) * DFEAT;
  const float* x2 = x1 + DFEAT;

  // forward-sign twiddle bases, shared across all 4 FFT calls
  cpx tw1 = make_float2(cos_rev((float)(j & 15) * (1.0f / 256.0f)),
                        -sin_rev((float)(j & 15) * (1.0f / 256.0f)));
  cpx tw2 = make_float2(cos_rev((float)j * (1.0f / 4096.0f)),
                        -sin_rev((float)j * (1.0f / 4096.0f)));

  cpx v[16];
#pragma unroll
  for (int r = 0; r < 16; ++r) {
    int pos = j + 256 * r;
    float ps = psi[pos];
    v[r] = make_float2(x1[pos] * ps, x2[pos] * ps);
  }
  fft_exchange<-1>(v, B, j, tw1, tw2);

  // park W in thread-private LDS slots (stride-1 per wave: conflict-free)
#pragma unroll
  for (int s = 0; s < 16; ++s) Wl[IDX(j + 256 * s)] = v[s];

  float a1[16], a2[16];
#pragma unroll
  for (int s = 0; s < 16; ++s) { a1[s] = 0.0f; a2[s] = 0.0f; }

  for (int r = 0; r < 3; ++r) {
#pragma unroll
    for (int q = 0; q < 16; ++q) {
      int pos = j + 256 * q;
      v[q] = cmulf(Wl[IDX(pos)], Ghat[r * DFEAT + pos]);
    }
    fft_exchange<1>(v, B, j, tw1, tw2);
#pragma unroll
    for (int s = 0; s < 16; ++s) {
      int pos = j + 256 * s;
      float om = omega[r * DFEAT + pos];
      a1[s] += v[s].x * om;
      a2[s] += v[s].y * om;
    }
  }

  float* o1 = out + ((size_t)(2 * p)) * DFEAT;
#pragma unroll
  for (int s = 0; s < 16; ++s) {
    int pos = j + 256 * s;
    float b = bias[pos];
    o1[pos] = a1[s] + b;
    o1[DFEAT + pos] = a2[s] + b;
  }
}

extern "C" void kernel_launch(void* const* d_in, const int* in_sizes, int n_in,
                              void* d_out, int out_size, void* d_ws, size_t ws_size,
                              hipStream_t stream) {
  const float* x     = (const float*)d_in[0];
  const float* psi   = (const float*)d_in[1];
  const float* omega = (const float*)d_in[2];
  const float* g     = (const float*)d_in[3];
  const float* bias  = (const float*)d_in[4];

  const int M = in_sizes[0] / DFEAT;   // 8192 rows

  cpx* Ghat = (cpx*)d_ws;              // 3 * 4096 * 8B = 96 KB

  ghat_kernel<<<3, NTH, 0, stream>>>(g, Ghat);
  fftconv_kernel<<<M / 2, NTH, 0, stream>>>(x, psi, omega, bias, Ghat,
                                            (float*)d_out);
}

// Round 20
// 147.300 us; speedup vs baseline: 1.1927x; 1.1927x over previous
//
#include <hip/hip_runtime.h>

#define DFEAT 4096
#define NTH 256

typedef float2 cpx;

__device__ __forceinline__ cpx cmulf(cpx a, cpx b) {
  return make_float2(a.x * b.x - a.y * b.y, a.x * b.y + a.y * b.x);
}

// pad 1 cpx every 16: uniform bank spread for stride-256 reads and stride-16 writes
#define IDX(i) ((i) + ((i) >> 4))
#define NPAD (DFEAT + DFEAT / 16)   // 4352 cpx = 34816 B

// sin/cos in REVOLUTIONS (hardware v_sin_f32 semantics); args here in [0, ~0.0625]
__device__ __forceinline__ float sin_rev(float rev) {
#if __has_builtin(__builtin_amdgcn_sinf)
  return __builtin_amdgcn_sinf(rev);
#else
  return __sinf(rev * 6.28318530717958647692f);
#endif
}
__device__ __forceinline__ float cos_rev(float rev) {
#if __has_builtin(__builtin_amdgcn_cosf)
  return __builtin_amdgcn_cosf(rev);
#else
  return __cosf(rev * 6.28318530717958647692f);
#endif
}

// DFT4 with sign SGN (-1 fwd, +1 inv), in-place on 4 cpx: out[s] in slot s
template <int SGN>
__device__ __forceinline__ void dft4(cpx& p0, cpx& p1, cpx& p2, cpx& p3) {
  cpx t0 = make_float2(p0.x + p2.x, p0.y + p2.y);
  cpx t1 = make_float2(p0.x - p2.x, p0.y - p2.y);
  cpx t2 = make_float2(p1.x + p3.x, p1.y + p3.y);
  cpx t3 = make_float2(p1.x - p3.x, p1.y - p3.y);
  cpx it3 = (SGN > 0) ? make_float2(-t3.y, t3.x) : make_float2(t3.y, -t3.x);
  p0 = make_float2(t0.x + t2.x, t0.y + t2.y);
  p2 = make_float2(t0.x - t2.x, t0.y - t2.y);
  p1 = make_float2(t1.x + it3.x, t1.y + it3.y);
  p3 = make_float2(t1.x - it3.x, t1.y - it3.y);
}

// W16^t = exp(SGN*2πi*t/16), compile-time t ∈ {1,2,3,4,6,9}
template <int SGN>
__device__ __forceinline__ cpx w16c(int t) {
  constexpr float C[10] = {1.f, 0.92387953251f, 0.70710678119f, 0.38268343236f, 0.f,
                           0.f, -0.70710678119f, 0.f, 0.f, -0.92387953251f};
  constexpr float S[10] = {0.f, 0.38268343236f, 0.70710678119f, 0.92387953251f, 1.f,
                           0.f, 0.70710678119f, 0.f, 0.f, -0.38268343236f};
  return make_float2(C[t], (SGN > 0) ? S[t] : -S[t]);
}

// 16-pt DFT, in-place: X[s] = sum_r v[r] exp(SGN 2πi rs/16), X[s] left in v[s].
template <int SGN>
__device__ __forceinline__ void dft16(cpx v[16]) {
#pragma unroll
  for (int r1 = 0; r1 < 4; ++r1) dft4<SGN>(v[r1], v[r1 + 4], v[r1 + 8], v[r1 + 12]);
  // v[r1 + 4*s1] = A[r1][s1]; apply W16^(r1*s1)
  v[5]  = cmulf(v[5],  w16c<SGN>(1));
  v[9]  = cmulf(v[9],  w16c<SGN>(2));
  v[13] = cmulf(v[13], w16c<SGN>(3));
  v[6]  = cmulf(v[6],  w16c<SGN>(2));
  v[10] = cmulf(v[10], w16c<SGN>(4));
  v[14] = cmulf(v[14], w16c<SGN>(6));
  v[7]  = cmulf(v[7],  w16c<SGN>(3));
  v[11] = cmulf(v[11], w16c<SGN>(6));
  v[15] = cmulf(v[15], w16c<SGN>(9));
  cpx t[16];
#pragma unroll
  for (int s1 = 0; s1 < 4; ++s1) {
    cpx p0 = v[4 * s1 + 0], p1 = v[4 * s1 + 1], p2 = v[4 * s1 + 2], p3 = v[4 * s1 + 3];
    dft4<SGN>(p0, p1, p2, p3);   // sum over r1; output slot q = s2
    t[s1] = p0; t[s1 + 4] = p1; t[s1 + 8] = p2; t[s1 + 12] = p3;
  }
#pragma unroll
  for (int s = 0; s < 16; ++s) v[s] = t[s];
}

// v[r] *= w^r, w = exp(SGN 2πi rev). Serial power chain: only 2 values live
// (binary powering variant spilled at the 128-VGPR budget — R19, WRITE +64 MB).
template <int SGN>
__device__ __forceinline__ void twiddle16(cpx v[16], float rev) {
  float s = sin_rev(rev), c = cos_rev(rev);
  cpx w1 = make_float2(c, (SGN > 0) ? s : -s);
  cpx w = w1;
  v[1] = cmulf(v[1], w);
#pragma unroll
  for (int r = 2; r < 16; ++r) { w = cmulf(w, w1); v[r] = cmulf(v[r], w); }
}

// 4096-pt FFT, radix-16 Stockham, 3 stages, 256 threads, 16 cpx/thread.
// Entry: v[r] = input at position j+256r. Exit: v[s] = output at position j+256s.
template <int SGN>
__device__ __forceinline__ void fft_exchange(cpx v[16], cpx* B, int j) {
  dft16<SGN>(v);                                  // st0 (Ns=1, no twiddle)
  __syncthreads();                                // prior consumers of B done
#pragma unroll
  for (int s = 0; s < 16; ++s) B[IDX(16 * j + s)] = v[s];
  __syncthreads();
#pragma unroll
  for (int r = 0; r < 16; ++r) v[r] = B[IDX(j + 256 * r)];
  __syncthreads();                                // all reads before in-place writes
  twiddle16<SGN>(v, (float)(j & 15) * (1.0f / 256.0f));
  dft16<SGN>(v);                                  // st1 (Ns=16)
#pragma unroll
  for (int s = 0; s < 16; ++s) B[IDX(256 * (j >> 4) + (j & 15) + 16 * s)] = v[s];
  __syncthreads();
#pragma unroll
  for (int r = 0; r < 16; ++r) v[r] = B[IDX(j + 256 * r)];
  twiddle16<SGN>(v, (float)j * (1.0f / 4096.0f));
  dft16<SGN>(v);                                  // st2 (Ns=256) -> natural order
}

// Ghat[r] = FFT(g[r]) / 4096
__global__ __launch_bounds__(NTH, 1) void ghat_kernel(const float* __restrict__ g,
                                                      cpx* __restrict__ Ghat) {
  __shared__ cpx B[NPAD];
  const int rr = blockIdx.x;
  const int j = threadIdx.x;
  cpx v[16];
#pragma unroll
  for (int r = 0; r < 16; ++r) {
    int pos = j + 256 * r;
    v[r] = make_float2(g[rr * DFEAT + pos], 0.0f);
  }
  fft_exchange<-1>(v, B, j);
  const float inv = 1.0f / 4096.0f;
#pragma unroll
  for (int s = 0; s < 16; ++s) {
    int pos = j + 256 * s;
    Ghat[rr * DFEAT + pos] = make_float2(v[s].x * inv, v[s].y * inv);
  }
}

// One block = one row PAIR (two-for-one):
//   w = x1*psi + i*x2*psi ; W = FFT(w), parked in THREAD-PRIVATE LDS slots
//   (each thread writes/reads only its own W entries -> no barriers, frees 32
//   VGPRs so the ~116-reg live set fits 2 blocks/CU without spilling)
//   for r: z = IFFT(W*Ghat_r); a1 += Re(z)*omega_r; a2 += Im(z)*omega_r
__global__ __launch_bounds__(NTH, 2) void fftconv_kernel(
    const float* __restrict__ x, const float* __restrict__ psi,
    const float* __restrict__ omega, const float* __restrict__ bias,
    const cpx* __restrict__ Ghat, float* __restrict__ out) {
  __shared__ cpx B[NPAD];
  __shared__ cpx Wl[NPAD];
  const int p = blockIdx.x;
  const int j = threadIdx.x;
  const float* x1 = x + ((size_t)(2 * p)) * DFEAT;
  const float* x2 = x1 + DFEAT;

  cpx v[16];
#pragma unroll
  for (int r = 0; r < 16; ++r) {
    int pos = j + 256 * r;
    float ps = psi[pos];
    v[r] = make_float2(x1[pos] * ps, x2[pos] * ps);
  }
  fft_exchange<-1>(v, B, j);

  // park W in thread-private LDS slots (stride-1 per wave: conflict-free)
#pragma unroll
  for (int s = 0; s < 16; ++s) Wl[IDX(j + 256 * s)] = v[s];

  float a1[16], a2[16];
#pragma unroll
  for (int s = 0; s < 16; ++s) { a1[s] = 0.0f; a2[s] = 0.0f; }

  for (int r = 0; r < 3; ++r) {
#pragma unroll
    for (int q = 0; q < 16; ++q) {
      int pos = j + 256 * q;
      v[q] = cmulf(Wl[IDX(pos)], Ghat[r * DFEAT + pos]);
    }
    fft_exchange<1>(v, B, j);
#pragma unroll
    for (int s = 0; s < 16; ++s) {
      int pos = j + 256 * s;
      float om = omega[r * DFEAT + pos];
      a1[s] += v[s].x * om;
      a2[s] += v[s].y * om;
    }
  }

  float* o1 = out + ((size_t)(2 * p)) * DFEAT;
#pragma unroll
  for (int s = 0; s < 16; ++s) {
    int pos = j + 256 * s;
    float b = bias[pos];
    o1[pos] = a1[s] + b;
    o1[DFEAT + pos] = a2[s] + b;
  }
}

extern "C" void kernel_launch(void* const* d_in, const int* in_sizes, int n_in,
                              void* d_out, int out_size, void* d_ws, size_t ws_size,
                              hipStream_t stream) {
  const float* x     = (const float*)d_in[0];
  const float* psi   = (const float*)d_in[1];
  const float* omega = (const float*)d_in[2];
  const float* g     = (const float*)d_in[3];
  const float* bias  = (const float*)d_in[4];

  const int M = in_sizes[0] / DFEAT;   // 8192 rows

  cpx* Ghat = (cpx*)d_ws;              // 3 * 4096 * 8B = 96 KB

  ghat_kernel<<<3, NTH, 0, stream>>>(g, Ghat);
  fftconv_kernel<<<M / 2, NTH, 0, stream>>>(x, psi, omega, bias, Ghat,
                                            (float*)d_out);
}